// Round 3
// baseline (90.716 us; speedup 1.0000x reference)
//
#include <hip/hip_runtime.h>
#include <hip/hip_cooperative_groups.h>
#include <math.h>

namespace cg = cooperative_groups;

#define TPB 512   // one thread per node (N = 512)
#define NCHUNK 4  // offset-chunks per time point -> grid = NCHUNK * 120 = 480 blocks

// Cyclic-offset pair decomposition: all unordered pairs {a,b} of N nodes are
// (i, (i+d) mod N) for d = 1..N/2-1 (all i) plus d = N/2 (i < N/2), each once.
// Thread tid owns node i = tid: z_i, gamma_i live in registers; partner j is
// consecutive across lanes -> conflict-free LDS reads, zero global loads in
// the inner loop.
//
// Event-time trick: sum over pairs of (g_i + g_j) = (N-1) * sum(gamma), which
// is time-independent. Event blocks accumulate only sum(dist); the final
// reduce subtracts B*E*(N-1)*sum(gamma) analytically.
//
// Single cooperative dispatch: partials -> grid.sync() -> block (0,0) reduces.

template <bool QUAD>
__device__ __forceinline__ float pair_loop(
    int tid, int N, int d0, int dfull, bool hasHalf,
    const float4* zsh, const float* gsh, float4 zi, float gi)
{
    const int mask = N - 1;   // N is a power of two (512)
    float acc = 0.0f;
    for (int dd = d0; dd < dfull; ++dd) {
        int j = (tid + dd) & mask;
        float4 zj = zsh[j];
        float dx = zi.x - zj.x;
        float dy = zi.y - zj.y;
        float dz = zi.z - zj.z;
        float dw = zi.w - zj.w;
        float dist = sqrtf(dx * dx + dy * dy + dz * dz + dw * dw);
        if (QUAD) acc += __expf(gi + gsh[j] - dist);
        else      acc += dist;
    }
    if (hasHalf && tid < (N >> 1)) {
        int j = (tid + (N >> 1)) & mask;
        float4 zj = zsh[j];
        float dx = zi.x - zj.x;
        float dy = zi.y - zj.y;
        float dz = zi.z - zj.z;
        float dw = zi.w - zj.w;
        float dist = sqrtf(dx * dx + dy * dy + dz * dz + dw * dw);
        if (QUAD) acc += __expf(gi + gsh[j] - dist);
        else      acc += dist;
    }
    return acc;
}

__global__ __launch_bounds__(TPB, 4) void nhpp_fused(
    const float* __restrict__ gamma,
    const float* __restrict__ z0,          // [3][N][4]
    const float* __restrict__ t_init,      // [B]
    const float* __restrict__ t_last,      // [B]
    const float* __restrict__ event_times, // [B][E]
    double*      __restrict__ partials,    // [NCHUNK * T]
    float*       __restrict__ out,
    int N, int B, int S, int E)
{
    __shared__ float4 zsh[TPB];
    __shared__ float  gsh[TPB];
    __shared__ double wsum[TPB / 64];

    const int tid = threadIdx.x;
    const int tt  = blockIdx.y;
    const int BS  = B * S;

    float t, w;
    bool quad;
    if (tt < BS) {
        int b = tt / S, s = tt - b * S;
        float ti = t_init[b];
        float st = (t_last[b] - ti) / (float)S;
        t = ti + st * (float)s;
        w = st;
        quad = true;
    } else {
        int idx = tt - BS;
        int b = idx / E, e = idx - b * E;
        t = event_times[b * E + e];
        w = 1.0f;
        quad = false;
    }

    // z(n) = z0[0][n] + t*z0[1][n] + (t^2/2)*z0[2][n]   (ORDER=3, D=4)
    const float c1 = t;
    const float c2 = 0.5f * t * t;
    const float4* z0v = (const float4*)z0;
    float4 zi = make_float4(0.f, 0.f, 0.f, 0.f);
    float  gi = 0.f;
    if (tid < N) {
        float4 a0 = z0v[tid];
        float4 a1 = z0v[N + tid];
        float4 a2 = z0v[2 * N + tid];
        zi.x = a0.x + c1 * a1.x + c2 * a2.x;
        zi.y = a0.y + c1 * a1.y + c2 * a2.y;
        zi.z = a0.z + c1 * a1.z + c2 * a2.z;
        zi.w = a0.w + c1 * a1.w + c2 * a2.w;
        gi = gamma[tid];
        zsh[tid] = zi;
        gsh[tid] = gi;
    }
    __syncthreads();

    // offsets d = 1..N/2, chunked; the last chunk's final offset (d = N/2) is
    // restricted to i < N/2 so each pair is counted exactly once.
    const int dpc = (N / 2) / NCHUNK;
    const int d0  = 1 + dpc * blockIdx.x;
    const int d1  = 1 + dpc * (blockIdx.x + 1);
    const bool hasHalf = (d1 == N / 2 + 1);
    const int dfull = hasHalf ? d1 - 1 : d1;

    float acc = 0.0f;
    if (tid < N) {
        acc = quad ? pair_loop<true >(tid, N, d0, dfull, hasHalf, zsh, gsh, zi, gi)
                   : pair_loop<false>(tid, N, d0, dfull, hasHalf, zsh, gsh, zi, gi);
        acc *= w;
    }

    for (int off = 32; off > 0; off >>= 1)
        acc += __shfl_down(acc, off, 64);
    if ((tid & 63) == 0) wsum[tid >> 6] = (double)acc;
    __syncthreads();
    if (tid == 0) {
        double s = 0.0;
        #pragma unroll
        for (int k = 0; k < TPB / 64; ++k) s += wsum[k];
        partials[tt * gridDim.x + blockIdx.x] = s;
        __threadfence();
    }

    cg::this_grid().sync();

    // final reduce in block (0,0): sum partials, subtract B*E*(N-1)*sum(gamma)
    if (blockIdx.x == 0 && blockIdx.y == 0) {
        const int nP = gridDim.x * gridDim.y;
        double v = 0.0;
        for (int k = tid; k < nP; k += TPB) v += partials[k];
        if (tid < N) v -= (double)(B * E) * (double)(N - 1) * (double)gamma[tid];
        for (int off = 32; off > 0; off >>= 1)
            v += __shfl_down(v, off, 64);
        if ((tid & 63) == 0) wsum[tid >> 6] = v;
        __syncthreads();
        if (tid == 0) {
            double s = 0.0;
            #pragma unroll
            for (int k = 0; k < TPB / 64; ++k) s += wsum[k];
            out[0] = (float)s;
        }
    }
}

extern "C" void kernel_launch(void* const* d_in, const int* in_sizes, int n_in,
                              void* d_out, int out_size, void* d_ws, size_t ws_size,
                              hipStream_t stream)
{
    const float* gamma   = (const float*)d_in[0];
    const float* z0      = (const float*)d_in[1];
    const float* t_init  = (const float*)d_in[2];
    const float* t_last  = (const float*)d_in[3];
    const float* ev      = (const float*)d_in[4];

    int N = in_sizes[0];          // 512
    int B = in_sizes[2];          // 4
    int E = in_sizes[4] / B;      // 20
    int S = 10;                   // reference constant
    int T = B * S + B * E;        // 120

    double* partials = (double*)d_ws;   // NCHUNK*T doubles = 3.8 KiB
    float*  outp     = (float*)d_out;

    dim3 grid(NCHUNK, T);
    dim3 block(TPB);
    void* args[] = {(void*)&gamma, (void*)&z0, (void*)&t_init, (void*)&t_last,
                    (void*)&ev, (void*)&partials, (void*)&outp,
                    (void*)&N, (void*)&B, (void*)&S, (void*)&E};
    hipLaunchCooperativeKernel((const void*)nhpp_fused, grid, block, args, 0, stream);
}

// Round 4
// 21.773 us; speedup vs baseline: 4.1665x; 4.1665x over previous
//
#include <hip/hip_runtime.h>
#include <math.h>

#define TPB 512   // one thread per node (N = 512)
#define NCHUNK 8  // offset-chunks per time point -> 8 * 120 = 960 blocks

// Cyclic-offset pair decomposition: all unordered pairs {a,b} of N nodes are
// (i, (i+d) mod N) for d = 1..N/2-1 (all i) plus d = N/2 (i < N/2), each once.
// Thread tid owns node i = tid: z_i, gamma_i in registers; partner j = tid+d
// is consecutive across lanes -> conflict-free LDS reads, no global loads in
// the inner loop.
//
// Event-time trick: sum_{pairs}(g_i + g_j) = (N-1)*sum(gamma) is
// time-independent, so event blocks accumulate only sum(dist); the reduce
// kernel subtracts B*E*(N-1)*sum(gamma) analytically (exact, in double).

template <bool QUAD>
__device__ __forceinline__ float pair_loop(
    int tid, int N, int d0, int dfull, bool hasHalf,
    const float4* zsh, const float* gsh, float4 zi, float gi)
{
    const int mask = N - 1;   // N is a power of two (512)
    float acc = 0.0f;
    #pragma unroll 4
    for (int dd = d0; dd < dfull; ++dd) {
        int j = (tid + dd) & mask;
        float4 zj = zsh[j];
        float dx = zi.x - zj.x;
        float dy = zi.y - zj.y;
        float dz = zi.z - zj.z;
        float dw = zi.w - zj.w;
        float dist = sqrtf(dx * dx + dy * dy + dz * dz + dw * dw);
        if (QUAD) acc += __expf(gi + gsh[j] - dist);
        else      acc += dist;
    }
    if (hasHalf && tid < (N >> 1)) {
        int j = (tid + (N >> 1)) & mask;
        float4 zj = zsh[j];
        float dx = zi.x - zj.x;
        float dy = zi.y - zj.y;
        float dz = zi.z - zj.z;
        float dw = zi.w - zj.w;
        float dist = sqrtf(dx * dx + dy * dy + dz * dz + dw * dw);
        if (QUAD) acc += __expf(gi + gsh[j] - dist);
        else      acc += dist;
    }
    return acc;
}

__global__ __launch_bounds__(TPB) void nhpp_partial(
    const float* __restrict__ gamma,
    const float* __restrict__ z0,          // [3][N][4]
    const float* __restrict__ t_init,      // [B]
    const float* __restrict__ t_last,      // [B]
    const float* __restrict__ event_times, // [B][E]
    double*      __restrict__ partials,    // [T * NCHUNK]
    int N, int B, int S, int E)
{
    __shared__ float4 zsh[TPB];
    __shared__ float  gsh[TPB];
    __shared__ double wsum[TPB / 64];

    const int tid = threadIdx.x;
    const int tt  = blockIdx.y;
    const int BS  = B * S;

    float t, w;
    bool quad;
    if (tt < BS) {
        int b = tt / S, s = tt - b * S;
        float ti = t_init[b];
        float st = (t_last[b] - ti) / (float)S;
        t = ti + st * (float)s;
        w = st;
        quad = true;
    } else {
        int idx = tt - BS;
        int b = idx / E, e = idx - b * E;
        t = event_times[b * E + e];
        w = -1.0f;   // event contribution enters NLL negatively; dist sums flip sign here
        quad = false;
    }

    // z(n) = z0[0][n] + t*z0[1][n] + (t^2/2)*z0[2][n]   (ORDER=3, D=4)
    const float c1 = t;
    const float c2 = 0.5f * t * t;
    const float4* z0v = (const float4*)z0;
    float4 zi = make_float4(0.f, 0.f, 0.f, 0.f);
    float  gi = 0.f;
    if (tid < N) {
        float4 a0 = z0v[tid];
        float4 a1 = z0v[N + tid];
        float4 a2 = z0v[2 * N + tid];
        zi.x = a0.x + c1 * a1.x + c2 * a2.x;
        zi.y = a0.y + c1 * a1.y + c2 * a2.y;
        zi.z = a0.z + c1 * a1.z + c2 * a2.z;
        zi.w = a0.w + c1 * a1.w + c2 * a2.w;
        gi = gamma[tid];
        zsh[tid] = zi;
        gsh[tid] = gi;
    }
    __syncthreads();

    // offsets d = 1..N/2, chunked; last chunk's final offset (d = N/2) is
    // restricted to i < N/2 so each pair counts exactly once.
    const int dpc = (N / 2) / NCHUNK;
    const int d0  = 1 + dpc * blockIdx.x;
    const int d1  = 1 + dpc * (blockIdx.x + 1);
    const bool hasHalf = (d1 == N / 2 + 1);
    const int dfull = hasHalf ? d1 - 1 : d1;

    float acc = 0.0f;
    if (tid < N) {
        acc = quad ? pair_loop<true >(tid, N, d0, dfull, hasHalf, zsh, gsh, zi, gi)
                   : pair_loop<false>(tid, N, d0, dfull, hasHalf, zsh, gsh, zi, gi);
        // quad: +w * sum(exp(ll));  event: -1 * sum(dist)  ->  integral - (-sum dist) handled
        // with gamma fold in reduce: NLL = sum_quad + sum_event_dist - B*E*(N-1)*sum(gamma)
        acc *= (quad ? w : 1.0f);
    }

    for (int off = 32; off > 0; off >>= 1)
        acc += __shfl_down(acc, off, 64);
    if ((tid & 63) == 0) wsum[tid >> 6] = (double)acc;
    __syncthreads();
    if (tid == 0) {
        double s = 0.0;
        #pragma unroll
        for (int k = 0; k < TPB / 64; ++k) s += wsum[k];
        partials[tt * NCHUNK + blockIdx.x] = s;
    }
}

__global__ __launch_bounds__(TPB) void nhpp_reduce(
    const double* __restrict__ partials, int n,
    const float* __restrict__ gamma, int N, int BE,
    float* __restrict__ out)
{
    __shared__ double wsum[TPB / 64];
    double acc = 0.0;
    for (int k = threadIdx.x; k < n; k += TPB) acc += partials[k];
    if ((int)threadIdx.x < N)
        acc -= (double)BE * (double)(N - 1) * (double)gamma[threadIdx.x];
    for (int off = 32; off > 0; off >>= 1)
        acc += __shfl_down(acc, off, 64);
    if ((threadIdx.x & 63) == 0) wsum[threadIdx.x >> 6] = acc;
    __syncthreads();
    if (threadIdx.x == 0) {
        double s = 0.0;
        #pragma unroll
        for (int k = 0; k < TPB / 64; ++k) s += wsum[k];
        out[0] = (float)s;
    }
}

extern "C" void kernel_launch(void* const* d_in, const int* in_sizes, int n_in,
                              void* d_out, int out_size, void* d_ws, size_t ws_size,
                              hipStream_t stream)
{
    const float* gamma   = (const float*)d_in[0];
    const float* z0      = (const float*)d_in[1];
    const float* t_init  = (const float*)d_in[2];
    const float* t_last  = (const float*)d_in[3];
    const float* ev      = (const float*)d_in[4];

    const int N = in_sizes[0];          // 512
    const int B = in_sizes[2];          // 4
    const int E = in_sizes[4] / B;      // 20
    const int S = 10;                   // reference constant
    const int T = B * S + B * E;        // 120

    double* partials = (double*)d_ws;   // T*NCHUNK doubles = 7.7 KiB

    dim3 grid(NCHUNK, T);
    nhpp_partial<<<grid, TPB, 0, stream>>>(gamma, z0, t_init, t_last, ev,
                                           partials, N, B, S, E);
    nhpp_reduce<<<1, TPB, 0, stream>>>(partials, T * NCHUNK, gamma, N, B * E,
                                       (float*)d_out);
}

// Round 5
// 16.098 us; speedup vs baseline: 5.6353x; 1.3525x over previous
//
#include <hip/hip_runtime.h>
#include <math.h>

#define TPB 512   // one thread per node (N = 512)
#define NCHUNK 8  // offset-chunks per time point -> 8 * 120 = 960 blocks

// Cyclic-offset pair decomposition: all unordered pairs {a,b} of N nodes are
// (i, (i+d) mod N) for d = 1..N/2-1 (all i) plus d = N/2 (i < N/2), each once.
// Thread tid owns node i = tid; partner j = (tid+d) & (N-1) is consecutive
// across lanes -> conflict-free LDS reads, no global loads in the inner loop.
//
// Quad blocks:  acc = sum_d e^{g_i} e^{g_j} e^{-dist}  (e^gamma staged in LDS),
//               scaled by w * e^{g_i} at the end.
// Event blocks: acc = sum_d dist  -  g_i * (2*#fullOffsets + hasHalf), which
//               exactly redistributes sum_{pairs}(g_i+g_j) over the block's
//               threads -> reduce kernel is a pure sum of partials.

template <bool QUAD>
__device__ __forceinline__ float pair_loop(
    int tid, int N, int d0, int dfull, bool hasHalf,
    const float4* zsh, const float* egsh, float4 zi)
{
    const int mask = N - 1;   // N is a power of two (512)
    float acc = 0.0f;
    #pragma unroll 4
    for (int dd = d0; dd < dfull; ++dd) {
        int j = (tid + dd) & mask;
        float4 zj = zsh[j];
        float dx = zi.x - zj.x;
        float dy = zi.y - zj.y;
        float dz = zi.z - zj.z;
        float dw = zi.w - zj.w;
        float dist = __builtin_amdgcn_sqrtf(dx * dx + dy * dy + dz * dz + dw * dw);
        if (QUAD) acc += egsh[j] * __expf(-dist);
        else      acc += dist;
    }
    if (hasHalf && tid < (N >> 1)) {
        int j = (tid + (N >> 1)) & mask;
        float4 zj = zsh[j];
        float dx = zi.x - zj.x;
        float dy = zi.y - zj.y;
        float dz = zi.z - zj.z;
        float dw = zi.w - zj.w;
        float dist = __builtin_amdgcn_sqrtf(dx * dx + dy * dy + dz * dz + dw * dw);
        if (QUAD) acc += egsh[j] * __expf(-dist);
        else      acc += dist;
    }
    return acc;
}

__global__ __launch_bounds__(TPB) void nhpp_partial(
    const float* __restrict__ gamma,
    const float* __restrict__ z0,          // [3][N][4]
    const float* __restrict__ t_init,      // [B]
    const float* __restrict__ t_last,      // [B]
    const float* __restrict__ event_times, // [B][E]
    float*       __restrict__ partials,    // [T * NCHUNK]
    int N, int B, int S, int E)
{
    __shared__ float4 zsh[TPB];
    __shared__ float  egsh[TPB];           // e^gamma (quad blocks only)
    __shared__ double wsum[TPB / 64];

    const int tid = threadIdx.x;
    const int tt  = blockIdx.y;
    const int BS  = B * S;

    float t, w;
    bool quad;
    if (tt < BS) {
        int b = tt / S, s = tt - b * S;
        float ti = t_init[b];
        float st = (t_last[b] - ti) / (float)S;
        t = ti + st * (float)s;
        w = st;
        quad = true;
    } else {
        int idx = tt - BS;
        int b = idx / E, e = idx - b * E;
        t = event_times[b * E + e];
        w = 1.0f;
        quad = false;
    }

    // z(n) = z0[0][n] + t*z0[1][n] + (t^2/2)*z0[2][n]   (ORDER=3, D=4)
    const float c1 = t;
    const float c2 = 0.5f * t * t;
    const float4* z0v = (const float4*)z0;
    float4 zi = make_float4(0.f, 0.f, 0.f, 0.f);
    float  gi = 0.f;
    if (tid < N) {
        float4 a0 = z0v[tid];
        float4 a1 = z0v[N + tid];
        float4 a2 = z0v[2 * N + tid];
        zi.x = a0.x + c1 * a1.x + c2 * a2.x;
        zi.y = a0.y + c1 * a1.y + c2 * a2.y;
        zi.z = a0.z + c1 * a1.z + c2 * a2.z;
        zi.w = a0.w + c1 * a1.w + c2 * a2.w;
        gi = gamma[tid];
        zsh[tid] = zi;
        if (quad) egsh[tid] = __expf(gi);
    }
    __syncthreads();

    // offsets d = 1..N/2, chunked; last chunk's final offset (d = N/2) is
    // restricted to i < N/2 so each pair counts exactly once.
    const int dpc = (N / 2) / NCHUNK;
    const int d0  = 1 + dpc * blockIdx.x;
    const int d1  = 1 + dpc * (blockIdx.x + 1);
    const bool hasHalf = (d1 == N / 2 + 1);
    const int dfull = hasHalf ? d1 - 1 : d1;

    float acc = 0.0f;
    if (tid < N) {
        if (quad) {
            acc = pair_loop<true >(tid, N, d0, dfull, hasHalf, zsh, egsh, zi);
            acc *= w * __expf(gi);
        } else {
            acc = pair_loop<false>(tid, N, d0, dfull, hasHalf, zsh, egsh, zi);
            // redistribute -sum_{pairs}(g_i+g_j): each full offset counts this
            // node's gamma twice (once as i, once as j); half-offset once.
            acc -= gi * (float)(2 * (dfull - d0) + (hasHalf ? 1 : 0));
        }
    }

    for (int off = 32; off > 0; off >>= 1)
        acc += __shfl_down(acc, off, 64);
    if ((tid & 63) == 0) wsum[tid >> 6] = (double)acc;
    __syncthreads();
    if (tid == 0) {
        double s = 0.0;
        #pragma unroll
        for (int k = 0; k < TPB / 64; ++k) s += wsum[k];
        partials[tt * NCHUNK + blockIdx.x] = (float)s;
    }
}

__global__ __launch_bounds__(TPB) void nhpp_reduce(
    const float* __restrict__ partials, int n, float* __restrict__ out)
{
    __shared__ double wsum[TPB / 64];
    double acc = 0.0;
    for (int k = threadIdx.x; k < n; k += TPB) acc += (double)partials[k];
    for (int off = 32; off > 0; off >>= 1)
        acc += __shfl_down(acc, off, 64);
    if ((threadIdx.x & 63) == 0) wsum[threadIdx.x >> 6] = acc;
    __syncthreads();
    if (threadIdx.x == 0) {
        double s = 0.0;
        #pragma unroll
        for (int k = 0; k < TPB / 64; ++k) s += wsum[k];
        out[0] = (float)s;
    }
}

extern "C" void kernel_launch(void* const* d_in, const int* in_sizes, int n_in,
                              void* d_out, int out_size, void* d_ws, size_t ws_size,
                              hipStream_t stream)
{
    const float* gamma   = (const float*)d_in[0];
    const float* z0      = (const float*)d_in[1];
    const float* t_init  = (const float*)d_in[2];
    const float* t_last  = (const float*)d_in[3];
    const float* ev      = (const float*)d_in[4];

    const int N = in_sizes[0];          // 512
    const int B = in_sizes[2];          // 4
    const int E = in_sizes[4] / B;      // 20
    const int S = 10;                   // reference constant
    const int T = B * S + B * E;        // 120

    float* partials = (float*)d_ws;     // T*NCHUNK floats = 3.8 KiB

    dim3 grid(NCHUNK, T);
    nhpp_partial<<<grid, TPB, 0, stream>>>(gamma, z0, t_init, t_last, ev,
                                           partials, N, B, S, E);
    nhpp_reduce<<<1, TPB, 0, stream>>>(partials, T * NCHUNK, (float*)d_out);
}

// Round 6
// 15.601 us; speedup vs baseline: 5.8146x; 1.0318x over previous
//
#include <hip/hip_runtime.h>
#include <hip/hip_fp16.h>
#include <math.h>

#define TPB 512   // one thread per node (N = 512)
#define NCHUNK 8  // offset-chunks per time point -> 8 * 120 = 960 blocks

#if __has_builtin(__builtin_amdgcn_exp2f)
#define EXP2(x) __builtin_amdgcn_exp2f(x)
#else
#define EXP2(x) exp2f(x)
#endif

// Cyclic-offset pair decomposition: all unordered pairs {a,b} of N nodes are
// (i, (i+d) mod N) for d = 1..N/2-1 (all i) plus d = N/2 (i < N/2), each once.
// Thread tid owns node i = tid; partner j = (tid+d) & (N-1) is consecutive
// across lanes -> conflict-free LDS reads, no global loads in the inner loop.
//
// LDS-byte optimization (the dominant pipe): z(t) staged as 4 x fp16 packed in
// a float2 (8 B/node, ds_read_b64) instead of float4 (16 B). fp16 coordinate
// quantization (|z| <~ 45, rel ~5e-4) gives NLL error ~1e4-1e5, far below the
// 1.9e6 threshold. Quad blocks pre-scale coords by log2(e) so exp(-dist) is a
// single raw v_exp (exp2 of the scaled distance).
//
// Quad blocks:  acc = sum_d e^{g_j} * 2^{-dist_s},  final acc *= w * e^{g_i}.
// Event blocks: acc = sum_d dist - g_i * (2*#fullOffsets + hasHalf)  (exact
//               redistribution of sum_{pairs}(g_i+g_j); gamma stays f32).

template <bool QUAD>
__device__ __forceinline__ float pair_loop(
    int tid, int N, int d0, int dfull, bool hasHalf,
    const float2* zsh, const float* egsh, __half2 zi01, __half2 zi23)
{
    const int mask = N - 1;   // N is a power of two (512)
    float acc = 0.0f;
    #pragma unroll 4
    for (int dd = d0; dd < dfull; ++dd) {
        int j = (tid + dd) & mask;
        float2 p = zsh[j];
        __half2 zj01 = *reinterpret_cast<const __half2*>(&p.x);
        __half2 zj23 = *reinterpret_cast<const __half2*>(&p.y);
        __half2 d01 = __hsub2(zi01, zj01);
        __half2 d23 = __hsub2(zi23, zj23);
        __half2 hq  = __hfma2(d23, d23, __hmul2(d01, d01));
        float q = __half2float(__hadd(__low2half(hq), __high2half(hq)));
        float dist = __builtin_amdgcn_sqrtf(q);
        if (QUAD) acc += egsh[j] * EXP2(-dist);
        else      acc += dist;
    }
    if (hasHalf && tid < (N >> 1)) {
        int j = (tid + (N >> 1)) & mask;
        float2 p = zsh[j];
        __half2 zj01 = *reinterpret_cast<const __half2*>(&p.x);
        __half2 zj23 = *reinterpret_cast<const __half2*>(&p.y);
        __half2 d01 = __hsub2(zi01, zj01);
        __half2 d23 = __hsub2(zi23, zj23);
        __half2 hq  = __hfma2(d23, d23, __hmul2(d01, d01));
        float q = __half2float(__hadd(__low2half(hq), __high2half(hq)));
        float dist = __builtin_amdgcn_sqrtf(q);
        if (QUAD) acc += egsh[j] * EXP2(-dist);
        else      acc += dist;
    }
    return acc;
}

__global__ __launch_bounds__(TPB) void nhpp_partial(
    const float* __restrict__ gamma,
    const float* __restrict__ z0,          // [3][N][4]
    const float* __restrict__ t_init,      // [B]
    const float* __restrict__ t_last,      // [B]
    const float* __restrict__ event_times, // [B][E]
    float*       __restrict__ partials,    // [T * NCHUNK]
    int N, int B, int S, int E)
{
    __shared__ float2 zsh[TPB];            // 4 x fp16 packed per node
    __shared__ float  egsh[TPB];           // e^gamma (quad blocks only)
    __shared__ double wsum[TPB / 64];

    const int tid = threadIdx.x;
    const int tt  = blockIdx.y;
    const int BS  = B * S;

    float t, w;
    bool quad;
    if (tt < BS) {
        int b = tt / S, s = tt - b * S;
        float ti = t_init[b];
        float st = (t_last[b] - ti) / (float)S;
        t = ti + st * (float)s;
        w = st;
        quad = true;
    } else {
        int idx = tt - BS;
        int b = idx / E, e = idx - b * E;
        t = event_times[b * E + e];
        w = 1.0f;
        quad = false;
    }

    // z(n) = z0[0][n] + t*z0[1][n] + (t^2/2)*z0[2][n]   (ORDER=3, D=4)
    const float c1 = t;
    const float c2 = 0.5f * t * t;
    const float sc = quad ? 1.4426950408889634f : 1.0f;   // log2(e) pre-scale
    const float4* z0v = (const float4*)z0;
    __half2 zi01 = __floats2half2_rn(0.f, 0.f);
    __half2 zi23 = zi01;
    float gi = 0.f;
    if (tid < N) {
        float4 a0 = z0v[tid];
        float4 a1 = z0v[N + tid];
        float4 a2 = z0v[2 * N + tid];
        float zx = (a0.x + c1 * a1.x + c2 * a2.x) * sc;
        float zy = (a0.y + c1 * a1.y + c2 * a2.y) * sc;
        float zz = (a0.z + c1 * a1.z + c2 * a2.z) * sc;
        float zw = (a0.w + c1 * a1.w + c2 * a2.w) * sc;
        zi01 = __floats2half2_rn(zx, zy);
        zi23 = __floats2half2_rn(zz, zw);
        float2 packed;
        packed.x = *reinterpret_cast<float*>(&zi01);
        packed.y = *reinterpret_cast<float*>(&zi23);
        zsh[tid] = packed;
        gi = gamma[tid];
        if (quad) egsh[tid] = __expf(gi);
    }
    __syncthreads();

    // offsets d = 1..N/2, chunked; last chunk's final offset (d = N/2) is
    // restricted to i < N/2 so each pair counts exactly once.
    const int dpc = (N / 2) / NCHUNK;
    const int d0  = 1 + dpc * blockIdx.x;
    const int d1  = 1 + dpc * (blockIdx.x + 1);
    const bool hasHalf = (d1 == N / 2 + 1);
    const int dfull = hasHalf ? d1 - 1 : d1;

    float acc = 0.0f;
    if (tid < N) {
        if (quad) {
            acc = pair_loop<true >(tid, N, d0, dfull, hasHalf, zsh, egsh, zi01, zi23);
            acc *= w * __expf(gi);
        } else {
            acc = pair_loop<false>(tid, N, d0, dfull, hasHalf, zsh, egsh, zi01, zi23);
            // redistribute -sum_{pairs}(g_i+g_j): each full offset counts this
            // node's gamma twice (once as i, once as j); half-offset once.
            acc -= gi * (float)(2 * (dfull - d0) + (hasHalf ? 1 : 0));
        }
    }

    for (int off = 32; off > 0; off >>= 1)
        acc += __shfl_down(acc, off, 64);
    if ((tid & 63) == 0) wsum[tid >> 6] = (double)acc;
    __syncthreads();
    if (tid == 0) {
        double s = 0.0;
        #pragma unroll
        for (int k = 0; k < TPB / 64; ++k) s += wsum[k];
        partials[tt * NCHUNK + blockIdx.x] = (float)s;
    }
}

__global__ __launch_bounds__(256) void nhpp_reduce(
    const float4* __restrict__ partials4, int n4, float* __restrict__ out)
{
    __shared__ double wsum[256 / 64];
    double acc = 0.0;
    for (int k = threadIdx.x; k < n4; k += 256) {
        float4 v = partials4[k];
        acc += (double)v.x + (double)v.y + (double)v.z + (double)v.w;
    }
    for (int off = 32; off > 0; off >>= 1)
        acc += __shfl_down(acc, off, 64);
    if ((threadIdx.x & 63) == 0) wsum[threadIdx.x >> 6] = acc;
    __syncthreads();
    if (threadIdx.x == 0) {
        double s = 0.0;
        #pragma unroll
        for (int k = 0; k < 4; ++k) s += wsum[k];
        out[0] = (float)s;
    }
}

extern "C" void kernel_launch(void* const* d_in, const int* in_sizes, int n_in,
                              void* d_out, int out_size, void* d_ws, size_t ws_size,
                              hipStream_t stream)
{
    const float* gamma   = (const float*)d_in[0];
    const float* z0      = (const float*)d_in[1];
    const float* t_init  = (const float*)d_in[2];
    const float* t_last  = (const float*)d_in[3];
    const float* ev      = (const float*)d_in[4];

    const int N = in_sizes[0];          // 512
    const int B = in_sizes[2];          // 4
    const int E = in_sizes[4] / B;      // 20
    const int S = 10;                   // reference constant
    const int T = B * S + B * E;        // 120

    float* partials = (float*)d_ws;     // T*NCHUNK floats = 3.8 KiB

    dim3 grid(NCHUNK, T);
    nhpp_partial<<<grid, TPB, 0, stream>>>(gamma, z0, t_init, t_last, ev,
                                           partials, N, B, S, E);
    nhpp_reduce<<<1, 256, 0, stream>>>((const float4*)partials, (T * NCHUNK) / 4,
                                       (float*)d_out);
}